// Round 5
// baseline (123.178 us; speedup 1.0000x reference)
//
#include <hip/hip_runtime.h>

#define DIM    512
#define RANK   64
#define TDIM   1024
#define BB     2
#define NROWS  (BB * TDIM)     // 2048 flattened rows per tensor
#define KSPLIT 4
#define KCH    (DIM / KSPLIT)  // 128 K-columns per proj block

typedef float v4f __attribute__((ext_vector_type(4)));
typedef float v2f __attribute__((ext_vector_type(2)));

__device__ __forceinline__ float fast_exp2(float x) { return __builtin_amdgcn_exp2f(x); }
__device__ __forceinline__ float fast_rcp(float x)  { return __builtin_amdgcn_rcpf(x); }

// ---------------------------------------------------------------------------
// Projection v3 (unchanged): split-K=4 into 4 SEPARATE buffers.
// grid = (NROWS/32, KSPLIT, 2) = 512 blocks (2/CU, 8 waves/CU).
// RANK-SLOT PERMUTATION: slots {4tx+j} hold logical ranks {tx+16j};
// pair_kernel permutes the weight vectors to match (sum over r invariant).
// ---------------------------------------------------------------------------
__global__ __launch_bounds__(256)
void proj_kernel(const float* __restrict__ tv, const float* __restrict__ sv,
                 const float* __restrict__ Wt, const float* __restrict__ Ws,
                 float* __restrict__ pt, float* __restrict__ ps)
{
    const int which = blockIdx.z;
    const float* X = which ? sv : tv;
    const float* W = which ? Ws : Wt;
    float* P = (which ? ps : pt) + (size_t)blockIdx.y * NROWS * RANK;

    const int row0 = blockIdx.x * 32;
    const int kc   = blockIdx.y * KCH;
    const int tid  = threadIdx.x;
    const int tx   = tid & 15;
    const int ty   = tid >> 4;

    __shared__ float xs[32][132];   // 16.9 KB
    __shared__ float wsm[64][132];  // 33.8 KB

#pragma unroll
    for (int p = 0; p < 4; p++) {
        const int li = p * 256 + tid;
        const int r  = li >> 5;
        const int c  = (li & 31) << 2;
        *(v4f*)&xs[r][c] = *(const v4f*)&X[(size_t)(row0 + r) * DIM + kc + c];
    }
#pragma unroll
    for (int p = 0; p < 8; p++) {
        const int li = p * 256 + tid;
        const int r  = li >> 5;
        const int c  = (li & 31) << 2;
        *(v4f*)&wsm[r][c] = *(const v4f*)&W[(size_t)r * DIM + kc + c];
    }
    __syncthreads();

    float acc[2][4];
#pragma unroll
    for (int i = 0; i < 2; i++)
#pragma unroll
        for (int j = 0; j < 4; j++) acc[i][j] = 0.f;

#pragma unroll 4
    for (int k4 = 0; k4 < KCH; k4 += 4) {
        v4f a[2], b[4];
#pragma unroll
        for (int i = 0; i < 2; i++)
            a[i] = *(const v4f*)&xs[ty + 16 * i][k4];   // broadcast per 16-group
#pragma unroll
        for (int j = 0; j < 4; j++)
            b[j] = *(const v4f*)&wsm[tx + 16 * j][k4];  // 2-way bank: free
#pragma unroll
        for (int i = 0; i < 2; i++)
#pragma unroll
            for (int j = 0; j < 4; j++) {
                acc[i][j] = fmaf(a[i].x, b[j].x, acc[i][j]);
                acc[i][j] = fmaf(a[i].y, b[j].y, acc[i][j]);
                acc[i][j] = fmaf(a[i].z, b[j].z, acc[i][j]);
                acc[i][j] = fmaf(a[i].w, b[j].w, acc[i][j]);
            }
    }

    // slot-permuted vector store: slots 4tx..4tx+3 hold logical ranks tx+16j
#pragma unroll
    for (int i = 0; i < 2; i++) {
        v4f o = {acc[i][0], acc[i][1], acc[i][2], acc[i][3]};
        *(v4f*)&P[(size_t)(row0 + ty + 16 * i) * RANK + tx * 4] = o;
    }
}

// ---------------------------------------------------------------------------
// Pairwise v6: 16(t) x 64(s) tile, 128 threads, micro 2x4,
// grid = (32, 64, 2) = 4096 blocks... no: (TDIM/64, TDIM/16, BB) = (16,64,2)
// = 2048 blocks -> 8 blocks/CU, 16 waves/CU.
// Combines the big-tile read amortization (7 ds_read_b128 per 8 quads) with
// the high wave count the 32x32 tile had. n-from-t algebra: nA = tA*wq
// (wq = iw/NL2E, exact since tA carries the NL2E prescale) removes the
// per-r4 nw-precompute. 4-way shared reciprocal unchanged -> same absmax.
// Per-CU pipe budget: LDS ~9us, trans ~8.5us, VALU ~7us, overlapped.
// ---------------------------------------------------------------------------
__global__ __launch_bounds__(128)
void pair_kernel(const float* __restrict__ pt, const float* __restrict__ ps,
                 const float* __restrict__ wt_out, const float* __restrict__ ws_out,
                 const float* __restrict__ iw, const float* __restrict__ bias_p,
                 float* __restrict__ out)
{
    const int b  = blockIdx.z;
    const int t0 = blockIdx.y * 16;
    const int s0 = blockIdx.x * 64;
    const int tid = threadIdx.x;
    const int tx  = tid & 15;
    const int tyy = tid >> 4;          // 0..7

    __shared__ float pts[16][68];             // pre-scaled by NL2E
    __shared__ float sts[64][68];
    __shared__ __align__(16) float wsh2[64];  // iw (slot-permuted) / NL2E
    __shared__ float wtsh[64];                // wt_out (slot-permuted) / NL2E
    __shared__ float wssh[64];                // ws_out (slot-permuted), raw
    __shared__ float tlsh[16];
    __shared__ float slsh[64];

    const float NL2E = -1.44269504088896340736f;  // -log2(e)
    const float INV_NL2E = -0.6931471805599453f;  // 1/NL2E = -ln(2)

    const size_t SPL = (size_t)NROWS * RANK;
    const float* ptb = pt + ((size_t)b * TDIM + t0) * RANK;
    const float* psb = ps + ((size_t)b * TDIM + s0) * RANK;

    // ---- stage pt rows (sum 4 K-splits, pre-scale): 16x16 v4f = 2/thread ----
#pragma unroll
    for (int p = 0; p < 2; p++) {
        const int li = p * 128 + tid;
        const int r  = li >> 4;          // 0..15
        const int c  = (li & 15) << 2;   // 0..60
        const float* src = ptb + (size_t)r * RANK + c;
        v4f v = *(const v4f*)src;
        v += *(const v4f*)(src + SPL);
        v += *(const v4f*)(src + 2 * SPL);
        v += *(const v4f*)(src + 3 * SPL);
        *(v4f*)&pts[r][c] = v * NL2E;
    }
    // ---- stage ps rows (raw): 64x16 v4f = 8/thread ----
#pragma unroll
    for (int p = 0; p < 8; p++) {
        const int li = p * 128 + tid;
        const int r  = li >> 4;          // 0..63
        const int c  = (li & 15) << 2;
        const float* src = psb + (size_t)r * RANK + c;
        v4f v = *(const v4f*)src;
        v += *(const v4f*)(src + SPL);
        v += *(const v4f*)(src + 2 * SPL);
        v += *(const v4f*)(src + 3 * SPL);
        *(v4f*)&sts[r][c] = v;
    }
    if (tid < 64) {
        const int lg = (tid >> 2) + 16 * (tid & 3);  // logical rank of slot tid
        wsh2[tid] = iw[lg] * INV_NL2E;     // tA*wsh2 = z*iw  (exact)
        wtsh[tid] = wt_out[lg] * INV_NL2E; // tl = sum pts'*wtsh = sum av*wt
        wssh[tid] = ws_out[lg];
    }
    __syncthreads();

    // per-block linear terms (disjoint waves do the two jobs)
    const float bias = bias_p[0];
    if (tid < 16) {
        float v = 0.f;
#pragma unroll 8
        for (int r = 0; r < RANK; r++) v = fmaf(pts[tid][r], wtsh[r], v);
        tlsh[tid] = v;
    } else if (tid >= 64) {
        const int s = tid - 64;
        float v = bias;
#pragma unroll 8
        for (int r = 0; r < RANK; r++) v = fmaf(sts[s][r], wssh[r], v);
        slsh[s] = v;   // bias folded in
    }
    __syncthreads();

    v2f acc2[2][4];
#pragma unroll
    for (int i = 0; i < 2; i++)
#pragma unroll
        for (int j = 0; j < 4; j++) acc2[i][j] = (v2f){0.f, 0.f};

#pragma unroll 2
    for (int r4 = 0; r4 < RANK; r4 += 4) {
        const v4f w2 = *(const v4f*)&wsh2[r4];
        const v2f wqA = {w2.x, w2.y};
        const v2f wqB = {w2.z, w2.w};

        v2f aA[2], aB[2];
#pragma unroll
        for (int i = 0; i < 2; i++) {
            const v4f av = *(const v4f*)&pts[tyy + 8 * i][r4];  // broadcast per 16-group
            aA[i] = (v2f){av.x, av.y};
            aB[i] = (v2f){av.z, av.w};
        }
        v2f bvA[4], bvB[4];
#pragma unroll
        for (int j = 0; j < 4; j++) {
            const v4f bb = *(const v4f*)&sts[tx + 16 * j][r4];  // 2-way bank: free
            bvA[j] = (v2f){bb.x, bb.y};
            bvB[j] = (v2f){bb.z, bb.w};
        }

#pragma unroll
        for (int i = 0; i < 2; i++)
#pragma unroll
            for (int j = 0; j < 4; j++) {
                const v2f tA = aA[i] * bvA[j];          // z*(-log2e) (pk_mul)
                const v2f tB = aB[i] * bvB[j];
                const float e0 = fast_exp2(tA.x);       // exp(-z)
                const float e1 = fast_exp2(tA.y);
                const float e2 = fast_exp2(tB.x);
                const float e3 = fast_exp2(tB.y);
                v2f dA = {e0, e1};  dA += 1.0f;         // pk_add
                v2f dB = {e2, e3};  dB += 1.0f;
                const v2f nA = tA * wqA;                // = z*iw (pk_mul, n-from-t)
                const v2f nB = tB * wqB;
                const float uA = fmaf(nA.y, dA.x, nA.x * dA.y);
                const float uB = fmaf(nB.y, dB.x, nB.x * dB.y);
                const float pA = dA.x * dA.y;
                const float pB = dB.x * dB.y;
                const float r  = fast_rcp(pA * pB);     // one rcp / 4 ranks
                const v2f rr = (v2f){pB, pA} * r;       // {1/(d0d1), 1/(d2d3)}
                acc2[i][j] += rr * (v2f){uA, uB};       // pk_fma
            }
    }

    // epilogue (horizontal add + linear terms; bias already in slsh)
#pragma unroll
    for (int i = 0; i < 2; i++) {
        const int t = t0 + tyy + 8 * i;
        const float tl = tlsh[tyy + 8 * i];
        float* orow = out + ((size_t)b * TDIM + t) * TDIM + s0;
#pragma unroll
        for (int j = 0; j < 4; j++) {
            orow[tx + 16 * j] = (acc2[i][j].x + acc2[i][j].y) + tl + slsh[tx + 16 * j];
        }
    }
}

// ---------------------------------------------------------------------------
extern "C" void kernel_launch(void* const* d_in, const int* in_sizes, int n_in,
                              void* d_out, int out_size, void* d_ws, size_t ws_size,
                              hipStream_t stream)
{
    const float* tv     = (const float*)d_in[0];  // [2,1024,512]
    const float* sv     = (const float*)d_in[1];  // [2,1024,512]
    const float* Wt     = (const float*)d_in[2];  // [64,512]
    const float* Ws     = (const float*)d_in[3];  // [64,512]
    const float* wt_out = (const float*)d_in[4];  // [64]
    const float* ws_out = (const float*)d_in[5];  // [64]
    const float* iw     = (const float*)d_in[6];  // [64]
    const float* bias   = (const float*)d_in[7];  // scalar
    float* out = (float*)d_out;                   // [2,1024,1024]

    const size_t SPL = (size_t)NROWS * RANK;      // 131072 floats
    float* pt = (float*)d_ws;                     // [KSPLIT][2048][64]
    float* ps = pt + (size_t)KSPLIT * SPL;        // [KSPLIT][2048][64]

    // no memset: every split slot is written exactly once
    dim3 pgrid(NROWS / 32, KSPLIT, 2);            // 512 blocks
    proj_kernel<<<pgrid, 256, 0, stream>>>(tv, sv, Wt, Ws, pt, ps);

    dim3 ggrid(TDIM / 64, TDIM / 16, BB);         // 2048 blocks, 8/CU
    pair_kernel<<<ggrid, 128, 0, stream>>>(pt, ps, wt_out, ws_out, iw, bias, out);
}

// Round 6
// 115.623 us; speedup vs baseline: 1.0653x; 1.0653x over previous
//
#include <hip/hip_runtime.h>

#define DIM    512
#define RANK   64
#define TDIM   1024
#define BB     2
#define NROWS  (BB * TDIM)     // 2048 flattened rows per tensor
#define KSPLIT 4
#define KCH    (DIM / KSPLIT)  // 128 K-columns per proj block

typedef float v4f __attribute__((ext_vector_type(4)));
typedef float v2f __attribute__((ext_vector_type(2)));

__device__ __forceinline__ float fast_exp2(float x) { return __builtin_amdgcn_exp2f(x); }
__device__ __forceinline__ float fast_rcp(float x)  { return __builtin_amdgcn_rcpf(x); }

// ---------------------------------------------------------------------------
// Projection v3 (unchanged): split-K=4 into 4 SEPARATE buffers.
// grid = (NROWS/32, KSPLIT, 2) = 512 blocks (2/CU, 8 waves/CU).
// RANK-SLOT PERMUTATION: slots {4tx+j} hold logical ranks {tx+16j};
// pair_kernel permutes the weight vectors to match (sum over r invariant).
// ---------------------------------------------------------------------------
__global__ __launch_bounds__(256)
void proj_kernel(const float* __restrict__ tv, const float* __restrict__ sv,
                 const float* __restrict__ Wt, const float* __restrict__ Ws,
                 float* __restrict__ pt, float* __restrict__ ps)
{
    const int which = blockIdx.z;
    const float* X = which ? sv : tv;
    const float* W = which ? Ws : Wt;
    float* P = (which ? ps : pt) + (size_t)blockIdx.y * NROWS * RANK;

    const int row0 = blockIdx.x * 32;
    const int kc   = blockIdx.y * KCH;
    const int tid  = threadIdx.x;
    const int tx   = tid & 15;
    const int ty   = tid >> 4;

    __shared__ float xs[32][132];   // 16.9 KB
    __shared__ float wsm[64][132];  // 33.8 KB

#pragma unroll
    for (int p = 0; p < 4; p++) {
        const int li = p * 256 + tid;
        const int r  = li >> 5;
        const int c  = (li & 31) << 2;
        *(v4f*)&xs[r][c] = *(const v4f*)&X[(size_t)(row0 + r) * DIM + kc + c];
    }
#pragma unroll
    for (int p = 0; p < 8; p++) {
        const int li = p * 256 + tid;
        const int r  = li >> 5;
        const int c  = (li & 31) << 2;
        *(v4f*)&wsm[r][c] = *(const v4f*)&W[(size_t)r * DIM + kc + c];
    }
    __syncthreads();

    float acc[2][4];
#pragma unroll
    for (int i = 0; i < 2; i++)
#pragma unroll
        for (int j = 0; j < 4; j++) acc[i][j] = 0.f;

#pragma unroll 4
    for (int k4 = 0; k4 < KCH; k4 += 4) {
        v4f a[2], b[4];
#pragma unroll
        for (int i = 0; i < 2; i++)
            a[i] = *(const v4f*)&xs[ty + 16 * i][k4];   // broadcast per 16-group
#pragma unroll
        for (int j = 0; j < 4; j++)
            b[j] = *(const v4f*)&wsm[tx + 16 * j][k4];  // 2-way bank: free
#pragma unroll
        for (int i = 0; i < 2; i++)
#pragma unroll
            for (int j = 0; j < 4; j++) {
                acc[i][j] = fmaf(a[i].x, b[j].x, acc[i][j]);
                acc[i][j] = fmaf(a[i].y, b[j].y, acc[i][j]);
                acc[i][j] = fmaf(a[i].z, b[j].z, acc[i][j]);
                acc[i][j] = fmaf(a[i].w, b[j].w, acc[i][j]);
            }
    }

    // slot-permuted vector store: slots 4tx..4tx+3 hold logical ranks tx+16j
#pragma unroll
    for (int i = 0; i < 2; i++) {
        v4f o = {acc[i][0], acc[i][1], acc[i][2], acc[i][3]};
        *(v4f*)&P[(size_t)(row0 + ty + 16 * i) * RANK + tx * 4] = o;
    }
}

// ---------------------------------------------------------------------------
// Pairwise v7: 64(t) x 64(s) tile, 512 threads, micro 2x4,
// grid = (16, 16, 2) = 512 blocks = EXACTLY 2 blocks/CU, both resident
// (LDS 36 KB x 2 = 72 KB < 160 KB) -> 16 waves/CU, 4/SIMD, single
// generation, no tail. Same per-quad instruction mix as v3 (7 ds_read per
// 8 quads) + v6's n-from-t (nA = tA*wq, exact). 4-way shared reciprocal
// unchanged -> absmax unchanged.
// Port model: per-SIMD trans ~41k cyc + VALU ~19k cyc; at 4 waves/SIMD the
// port should stay >80% busy -> pair ~30 us (was 43.9 at 2 waves/SIMD).
// ---------------------------------------------------------------------------
__global__ __launch_bounds__(512)
void pair_kernel(const float* __restrict__ pt, const float* __restrict__ ps,
                 const float* __restrict__ wt_out, const float* __restrict__ ws_out,
                 const float* __restrict__ iw, const float* __restrict__ bias_p,
                 float* __restrict__ out)
{
    const int b  = blockIdx.z;
    const int t0 = blockIdx.y * 64;
    const int s0 = blockIdx.x * 64;
    const int tid = threadIdx.x;
    const int tx  = tid & 15;
    const int ty  = tid >> 4;          // 0..31

    __shared__ float pts[64][68];             // pre-scaled by NL2E (17.4 KB)
    __shared__ float sts[64][68];             // raw (17.4 KB)
    __shared__ __align__(16) float wsh2[64];  // iw (slot-permuted) / NL2E
    __shared__ float wtsh[64];                // wt_out (slot-permuted) / NL2E
    __shared__ float wssh[64];                // ws_out (slot-permuted), raw
    __shared__ float tlsh[64];
    __shared__ float slsh[64];

    const float NL2E = -1.44269504088896340736f;  // -log2(e)
    const float INV_NL2E = -0.6931471805599453f;  // 1/NL2E = -ln(2)

    const size_t SPL = (size_t)NROWS * RANK;
    const float* ptb = pt + ((size_t)b * TDIM + t0) * RANK;
    const float* psb = ps + ((size_t)b * TDIM + s0) * RANK;

    // ---- stage pt rows (sum 4 K-splits, pre-scale): 64x16 v4f = 2/thread ----
#pragma unroll
    for (int p = 0; p < 2; p++) {
        const int li = p * 512 + tid;
        const int r  = li >> 4;          // 0..63
        const int c  = (li & 15) << 2;   // 0..60
        const float* src = ptb + (size_t)r * RANK + c;
        v4f v = *(const v4f*)src;
        v += *(const v4f*)(src + SPL);
        v += *(const v4f*)(src + 2 * SPL);
        v += *(const v4f*)(src + 3 * SPL);
        *(v4f*)&pts[r][c] = v * NL2E;
    }
    // ---- stage ps rows (raw): 64x16 v4f = 2/thread ----
#pragma unroll
    for (int p = 0; p < 2; p++) {
        const int li = p * 512 + tid;
        const int r  = li >> 4;
        const int c  = (li & 15) << 2;
        const float* src = psb + (size_t)r * RANK + c;
        v4f v = *(const v4f*)src;
        v += *(const v4f*)(src + SPL);
        v += *(const v4f*)(src + 2 * SPL);
        v += *(const v4f*)(src + 3 * SPL);
        *(v4f*)&sts[r][c] = v;
    }
    if (tid < 64) {
        const int lg = (tid >> 2) + 16 * (tid & 3);  // logical rank of slot tid
        wsh2[tid] = iw[lg] * INV_NL2E;     // tA*wsh2 = z*iw  (exact)
        wtsh[tid] = wt_out[lg] * INV_NL2E; // tl = sum pts'*wtsh = sum av*wt
        wssh[tid] = ws_out[lg];
    }
    __syncthreads();

    // per-block linear terms (disjoint waves do the two jobs)
    const float bias = bias_p[0];
    if (tid < 64) {
        float v = 0.f;
#pragma unroll 8
        for (int r = 0; r < RANK; r++) v = fmaf(pts[tid][r], wtsh[r], v);
        tlsh[tid] = v;
    } else if (tid < 128) {
        const int s = tid - 64;
        float v = bias;
#pragma unroll 8
        for (int r = 0; r < RANK; r++) v = fmaf(sts[s][r], wssh[r], v);
        slsh[s] = v;   // bias folded in
    }
    __syncthreads();

    v2f acc2[2][4];
#pragma unroll
    for (int i = 0; i < 2; i++)
#pragma unroll
        for (int j = 0; j < 4; j++) acc2[i][j] = (v2f){0.f, 0.f};

#pragma unroll 2
    for (int r4 = 0; r4 < RANK; r4 += 4) {
        const v4f w2 = *(const v4f*)&wsh2[r4];
        const v2f wqA = {w2.x, w2.y};
        const v2f wqB = {w2.z, w2.w};

        v2f aA[2], aB[2];
#pragma unroll
        for (int i = 0; i < 2; i++) {
            const v4f av = *(const v4f*)&pts[ty + 32 * i][r4];  // broadcast per 16-group
            aA[i] = (v2f){av.x, av.y};
            aB[i] = (v2f){av.z, av.w};
        }
        v2f bvA[4], bvB[4];
#pragma unroll
        for (int j = 0; j < 4; j++) {
            const v4f bb = *(const v4f*)&sts[tx + 16 * j][r4];  // 2-way bank: free
            bvA[j] = (v2f){bb.x, bb.y};
            bvB[j] = (v2f){bb.z, bb.w};
        }

#pragma unroll
        for (int i = 0; i < 2; i++)
#pragma unroll
            for (int j = 0; j < 4; j++) {
                const v2f tA = aA[i] * bvA[j];          // z*(-log2e) (pk_mul)
                const v2f tB = aB[i] * bvB[j];
                const float e0 = fast_exp2(tA.x);       // exp(-z)
                const float e1 = fast_exp2(tA.y);
                const float e2 = fast_exp2(tB.x);
                const float e3 = fast_exp2(tB.y);
                v2f dA = {e0, e1};  dA += 1.0f;         // pk_add
                v2f dB = {e2, e3};  dB += 1.0f;
                const v2f nA = tA * wqA;                // = z*iw (pk_mul, n-from-t)
                const v2f nB = tB * wqB;
                const float uA = fmaf(nA.y, dA.x, nA.x * dA.y);
                const float uB = fmaf(nB.y, dB.x, nB.x * dB.y);
                const float pA = dA.x * dA.y;
                const float pB = dB.x * dB.y;
                const float r  = fast_rcp(pA * pB);     // one rcp / 4 ranks
                const v2f rr = (v2f){pB, pA} * r;       // {1/(d0d1), 1/(d2d3)}
                acc2[i][j] += rr * (v2f){uA, uB};       // pk_fma
            }
    }

    // epilogue (horizontal add + linear terms; bias already in slsh)
#pragma unroll
    for (int i = 0; i < 2; i++) {
        const int t = t0 + ty + 32 * i;
        const float tl = tlsh[ty + 32 * i];
        float* orow = out + ((size_t)b * TDIM + t) * TDIM + s0;
#pragma unroll
        for (int j = 0; j < 4; j++) {
            orow[tx + 16 * j] = (acc2[i][j].x + acc2[i][j].y) + tl + slsh[tx + 16 * j];
        }
    }
}

// ---------------------------------------------------------------------------
extern "C" void kernel_launch(void* const* d_in, const int* in_sizes, int n_in,
                              void* d_out, int out_size, void* d_ws, size_t ws_size,
                              hipStream_t stream)
{
    const float* tv     = (const float*)d_in[0];  // [2,1024,512]
    const float* sv     = (const float*)d_in[1];  // [2,1024,512]
    const float* Wt     = (const float*)d_in[2];  // [64,512]
    const float* Ws     = (const float*)d_in[3];  // [64,512]
    const float* wt_out = (const float*)d_in[4];  // [64]
    const float* ws_out = (const float*)d_in[5];  // [64]
    const float* iw     = (const float*)d_in[6];  // [64]
    const float* bias   = (const float*)d_in[7];  // scalar
    float* out = (float*)d_out;                   // [2,1024,1024]

    const size_t SPL = (size_t)NROWS * RANK;      // 131072 floats
    float* pt = (float*)d_ws;                     // [KSPLIT][2048][64]
    float* ps = pt + (size_t)KSPLIT * SPL;        // [KSPLIT][2048][64]

    // no memset: every split slot is written exactly once
    dim3 pgrid(NROWS / 32, KSPLIT, 2);            // 512 blocks
    proj_kernel<<<pgrid, 256, 0, stream>>>(tv, sv, Wt, Ws, pt, ps);

    dim3 ggrid(TDIM / 64, TDIM / 64, BB);         // 512 blocks, 2/CU resident
    pair_kernel<<<ggrid, 512, 0, stream>>>(pt, ps, wt_out, ws_out, iw, bias, out);
}